// Round 16
// baseline (186.653 us; speedup 1.0000x reference)
//
#include <hip/hip_runtime.h>
#include <hip/hip_bf16.h>

#define N_ 8
#define C_ 32
#define H_ 64
#define W_ 64
#define HW_ (H_*W_)
#define NHW_ (N_*HW_)
#define INTER_ 64
#define BC_ 108
#define KS_ 7
#define K2_ (KS_*KS_)
#define NB_ 6
#define TB_ 18
#define OUT_ 64
#define DDIM_ (C_*NB_)   // 192
#define P2CH_ 288        // 9 tp-pairs * 32 c

typedef __attribute__((ext_vector_type(8))) short short8;
typedef __attribute__((ext_vector_type(4))) float f32x4;
typedef __attribute__((ext_vector_type(2))) float f32x2;

__device__ __forceinline__ unsigned short f2bf(float f) {
    union { float f; unsigned u; } v; v.f = f;
    unsigned r = v.u + 0x7fffu + ((v.u >> 16) & 1u);
    return (unsigned short)(r >> 16);
}
__device__ __forceinline__ float bf2f(unsigned short h) {
    return __uint_as_float((unsigned int)h << 16);
}

__device__ __forceinline__ short8 frag4(const unsigned int* p) {
    union { unsigned int u[4]; short8 s; } v;
    v.u[0] = p[0]; v.u[1] = p[1]; v.u[2] = p[2]; v.u[3] = p[3];
    return v.s;
}

// ---------------------------------------------------------------------------
// k_prep: one-time weight conversions + basesM packing + BN-partial zeroing.
// basesM: A-fragment table for the MFMA pconv, layout [mt][ks][lane][j] bf16.
// k' = ky*8 + kx (K padded 49->64): lane(q,n15) holds A[m=n15][k=q*8+j] of
// k-step ks -> ky = ks*4+q, kx = j; zero at tp2>=18 | ky>=7 | kx>=7.
__global__ __launch_bounds__(256) void k_prep(const float* __restrict__ w1,
                                              const float* __restrict__ w2,
                                              const float* __restrict__ ow,
                                              const float* __restrict__ bases,
                                              unsigned short* __restrict__ wb1,
                                              unsigned short* __restrict__ wb2,
                                              unsigned short* __restrict__ wbp,
                                              unsigned short* __restrict__ basesM,
                                              float* __restrict__ pz) {
    int bid = blockIdx.x, t = threadIdx.x;
    if (bid < 72) {
        int i = bid * 256 + t;                // < 18432 = 9*64*32
        int ci = i & 31, co = (i >> 5) & 63, s = i >> 11;
        wb1[i] = f2bf(w1[((co << 5) + ci) * 9 + s]);   // wb1[s*2048 + co*32 + ci]
    } else if (bid < 360) {
        int i = (bid - 72) * 256 + t;         // < 73728 = 9*128*64
        int ci = i & 63, co = (i >> 6) & 127, s = i >> 13;
        unsigned short v = 0;
        if (co < BC_) v = f2bf(w2[((co << 6) + ci) * 9 + s]);
        wb2[i] = v;
    } else if (bid < 408) {
        int i = (bid - 360) * 256 + t;        // < 12288 = 64*192
        if (i < OUT_ * DDIM_) {
            float v = ow[i];
            unsigned short hi = f2bf(v);
            wbp[i] = hi;
            wbp[OUT_ * DDIM_ + i] = f2bf(v - bf2f(hi));
        }
    } else if (bid == 408) {
        // zero part1|part2: (INTER_+BC_)*8 float2 = 2752 floats
        for (int i = t; i < (INTER_ + BC_) * 8 * 2; i += 256) pz[i] = 0.f;
    } else {
        // basesM: 2mt * 2ks * 64lane * 8j = 2048 bf16
        for (int i = t; i < 2048; i += 256) {
            int j = i & 7, lane = (i >> 3) & 63, sk = (i >> 9) & 1, mt = i >> 10;
            int q = lane >> 4, n15 = lane & 15;
            int tp2 = mt * 16 + n15;
            int ky = sk * 4 + q, kx = j;
            unsigned short v = 0;
            if (tp2 < TB_ && ky < 7 && kx < 7)
                v = f2bf(bases[tp2 * K2_ + ky * 7 + kx]);
            basesM[i] = v;
        }
    }
}

// ---------------------------------------------------------------------------
// k_front: horizontal fusion of (pconv-MFMA | conv1-direct), 1:1 interleave.
// pconv as MFMA GEMM: P[tp2][px] = sum_k bases[tp2][k] * patch[k][px],
// k' = ky*8+kx. B-col n15 -> pixels {2n15, 2n15+1, 2n15+32, 2n15+33}: the
// aligned u32 window d[0..4] (elements 2n15..2n15+9, 4B-aligned) yields f0
// directly and f1 by 16-bit funnel shift (v_alignbit). Adjacent pixel pairs
// give 8B-coalesced dwordx2 P2 stores.
__global__ __launch_bounds__(256) void k_front(const float* __restrict__ x,
                                               const unsigned short* __restrict__ basesM,
                                               const unsigned short* __restrict__ wb1,
                                               const float* __restrict__ b1,
                                               unsigned int* __restrict__ P2,
                                               float* __restrict__ y1,
                                               float2* __restrict__ part1) {
    __shared__ __align__(16) char smem[16896];
    int bid = blockIdx.x, t = threadIdx.x;
    int g = bid >> 1, fr = bid & 1;      // 1:1 interleave

    if (fr == 0) {
        // ---- pconv family (MFMA): pid -> (n, c, rg) ----
        unsigned short* xt = (unsigned short*)smem;   // [23][72] bf16, col shift 3
        int rg = g & 3;
        int c  = (g >> 2) & 31;
        int n  = g >> 7;
        int h0 = rg << 4;
        int lane = t & 63, wv = t >> 6;
        int q = lane >> 4, n15 = lane & 15;

        const float* xc = x + (((size_t)n * C_ + c) << 12);
        for (int i = t; i < 23 * 72; i += 256) {
            int r = i / 72, cl = i % 72;
            int gr = h0 - 3 + r, gc = cl - 3;
            float v = 0.f;
            if (r < 22 && gr >= 0 && gr < H_ && gc >= 0 && gc < W_)
                v = xc[(gr << 6) + gc];
            xt[i] = f2bf(v);
        }
        __syncthreads();

        short8 afr[2][2];
        #pragma unroll
        for (int mt = 0; mt < 2; mt++)
            #pragma unroll
            for (int sk = 0; sk < 2; sk++)
                afr[mt][sk] = *(const short8*)(basesM + ((mt * 2 + sk) * 64 + lane) * 8);

        #pragma unroll 1
        for (int rr = 0; rr < 4; rr++) {
            int hrow = wv * 4 + rr;          // 0..15
            int h = h0 + hrow;
            f32x4 acc[4][2];                 // [cc: px 2n15,2n15+1,2n15+32,2n15+33][mt]
            #pragma unroll
            for (int cc = 0; cc < 4; cc++) {
                acc[cc][0] = (f32x4){0.f, 0.f, 0.f, 0.f};
                acc[cc][1] = (f32x4){0.f, 0.f, 0.f, 0.f};
            }
            #pragma unroll
            for (int sk = 0; sk < 2; sk++) {
                // aligned u32 window: elements 2n15.. (u32 index row*36+n15)
                const unsigned int* rp32 = (const unsigned int*)xt +
                                           (hrow + sk * 4 + q) * 36 + n15;
                unsigned int d0 = rp32[0], d1 = rp32[1], d2 = rp32[2],
                             d3 = rp32[3], d4 = rp32[4];
                unsigned int e0 = rp32[16], e1 = rp32[17], e2 = rp32[18],
                             e3 = rp32[19], e4 = rp32[20];
                union { unsigned int u[4]; short8 s; } f0, f1, f2v, f3v;
                f0.u[0] = d0; f0.u[1] = d1; f0.u[2] = d2; f0.u[3] = d3;
                f1.u[0] = (d0 >> 16) | (d1 << 16);
                f1.u[1] = (d1 >> 16) | (d2 << 16);
                f1.u[2] = (d2 >> 16) | (d3 << 16);
                f1.u[3] = (d3 >> 16) | (d4 << 16);
                f2v.u[0] = e0; f2v.u[1] = e1; f2v.u[2] = e2; f2v.u[3] = e3;
                f3v.u[0] = (e0 >> 16) | (e1 << 16);
                f3v.u[1] = (e1 >> 16) | (e2 << 16);
                f3v.u[2] = (e2 >> 16) | (e3 << 16);
                f3v.u[3] = (e3 >> 16) | (e4 << 16);
                acc[0][0] = __builtin_amdgcn_mfma_f32_16x16x32_bf16(afr[0][sk], f0.s, acc[0][0], 0, 0, 0);
                acc[0][1] = __builtin_amdgcn_mfma_f32_16x16x32_bf16(afr[1][sk], f0.s, acc[0][1], 0, 0, 0);
                acc[1][0] = __builtin_amdgcn_mfma_f32_16x16x32_bf16(afr[0][sk], f1.s, acc[1][0], 0, 0, 0);
                acc[1][1] = __builtin_amdgcn_mfma_f32_16x16x32_bf16(afr[1][sk], f1.s, acc[1][1], 0, 0, 0);
                acc[2][0] = __builtin_amdgcn_mfma_f32_16x16x32_bf16(afr[0][sk], f2v.s, acc[2][0], 0, 0, 0);
                acc[2][1] = __builtin_amdgcn_mfma_f32_16x16x32_bf16(afr[1][sk], f2v.s, acc[2][1], 0, 0, 0);
                acc[3][0] = __builtin_amdgcn_mfma_f32_16x16x32_bf16(afr[0][sk], f3v.s, acc[3][0], 0, 0, 0);
                acc[3][1] = __builtin_amdgcn_mfma_f32_16x16x32_bf16(afr[1][sk], f3v.s, acc[3][1], 0, 0, 0);
            }
            // stores: D row m=q*4+reg -> tp2; pairs (reg0,reg1)->tp=2q,
            // (reg2,reg3)->tp=2q+1; mt=1 q==0 -> tp=8. Adjacent px pair ->
            // one 8B store at col 2n15 (+32 for pp=1).
            size_t pb = ((size_t)n * P2CH_) << 12;
            #pragma unroll
            for (int pp = 0; pp < 2; pp++) {
                int ccb = pp * 2;
                int colb = 2 * n15 + pp * 32;
                unsigned int lo0 = (unsigned int)f2bf(acc[ccb][0][0]) |
                                   ((unsigned int)f2bf(acc[ccb][0][1]) << 16);
                unsigned int hi0 = (unsigned int)f2bf(acc[ccb + 1][0][0]) |
                                   ((unsigned int)f2bf(acc[ccb + 1][0][1]) << 16);
                unsigned int lo1 = (unsigned int)f2bf(acc[ccb][0][2]) |
                                   ((unsigned int)f2bf(acc[ccb][0][3]) << 16);
                unsigned int hi1 = (unsigned int)f2bf(acc[ccb + 1][0][2]) |
                                   ((unsigned int)f2bf(acc[ccb + 1][0][3]) << 16);
                *(unsigned long long*)&P2[pb + (((size_t)(2 * q) * 32 + c) << 12) + (h << 6) + colb] =
                    (unsigned long long)lo0 | ((unsigned long long)hi0 << 32);
                *(unsigned long long*)&P2[pb + (((size_t)(2 * q + 1) * 32 + c) << 12) + (h << 6) + colb] =
                    (unsigned long long)lo1 | ((unsigned long long)hi1 << 32);
                if (q == 0) {
                    unsigned int lo8 = (unsigned int)f2bf(acc[ccb][1][0]) |
                                       ((unsigned int)f2bf(acc[ccb][1][1]) << 16);
                    unsigned int hi8 = (unsigned int)f2bf(acc[ccb + 1][1][0]) |
                                       ((unsigned int)f2bf(acc[ccb + 1][1][1]) << 16);
                    *(unsigned long long*)&P2[pb + (((size_t)8 * 32 + c) << 12) + (h << 6) + colb] =
                        (unsigned long long)lo8 | ((unsigned long long)hi8 << 32);
                }
            }
        }
    } else {
        // ---- conv1 family: COG=32, ROWS=1, weights from global wb1 ----
        // LDS carve: sx1[198][40] bf16 (15840B) | sbp[4][64] f32 (1024B)
        unsigned short* sx1 = (unsigned short*)smem;
        float* sbp = (float*)(sx1 + 198 * 40);   // offset 15840 (16-aligned)

        int cid = g;                   // 0..1023
        int n = cid >> 7;              // 0..7
        int rem = cid & 127;
        int co0 = (rem & 1) << 5;      // 2 co-halves of 32
        int h0 = rem >> 1;             // 64 rows
        int lane = t & 63, wv = t >> 6;
        int q = lane >> 4, n15 = lane & 15;

        // stage x tile: rows h0-1..h0+1, cols 1..64 (x cols 0..63), 32 ch, bf16
        for (int e = t; e < 1536; e += 256) {
            int c = e & 31, rc4 = e >> 5;        // rc4 in 0..47
            int r = rc4 >> 4, cq = rc4 & 15;     // r 0..2, cq 0..15
            int hh = h0 - 1 + r;
            bool rok = (hh >= 0 && hh < H_);
            float4 v = {0.f, 0.f, 0.f, 0.f};
            if (rok) v = *(const float4*)(x + (((size_t)n * C_ + c) << 12) + (hh << 6) + cq * 4);
            unsigned short* d = sx1 + (r * 66 + 1 + cq * 4) * 40 + c;
            d[0]   = f2bf(v.x);
            d[40]  = f2bf(v.y);
            d[80]  = f2bf(v.z);
            d[120] = f2bf(v.w);
        }
        // border zeros: cols 0 and 65, 3 rows x 32 channels
        if (t < 96) {
            int c = t & 31, r = t >> 5;
            sx1[(r * 66 + 0) * 40 + c] = 0;
            sx1[(r * 66 + 65) * 40 + c] = 0;
        }
        __syncthreads();

        f32x4 acc[2];
        acc[0] = (f32x4){0.f, 0.f, 0.f, 0.f};
        acc[1] = (f32x4){0.f, 0.f, 0.f, 0.f};
        #pragma unroll
        for (int s = 0; s < 9; s++) {
            int dy = s / 3, dx = s % 3;
            short8 bfr = *(const short8*)(sx1 + (dy * 66 + wv * 16 + n15 + dx) * 40 + q * 8);
            #pragma unroll
            for (int mt = 0; mt < 2; mt++) {
                short8 afr = *(const short8*)(wb1 + s * 2048 + (co0 + mt * 16 + n15) * 32 + q * 8);
                acc[mt] = __builtin_amdgcn_mfma_f32_16x16x32_bf16(afr, bfr, acc[mt], 0, 0, 0);
            }
        }

        // epilogue: store y1 + BN1 partial stats
        int wcol = wv * 16 + n15;
        float sa[2][4], sa2[2][4];
        #pragma unroll
        for (int mt = 0; mt < 2; mt++)
            #pragma unroll
            for (int reg = 0; reg < 4; reg++) {
                int co = co0 + mt * 16 + q * 4 + reg;
                float v = acc[mt][reg] + b1[co];
                y1[(((size_t)n * INTER_ + co) << 12) + (h0 << 6) + wcol] = v;
                sa[mt][reg] = v; sa2[mt][reg] = v * v;
            }
        #pragma unroll
        for (int mt = 0; mt < 2; mt++)
            #pragma unroll
            for (int reg = 0; reg < 4; reg++) {
                float s = sa[mt][reg], s2 = sa2[mt][reg];
                #pragma unroll
                for (int off = 1; off < 16; off <<= 1) {
                    s += __shfl_xor(s, off);
                    s2 += __shfl_xor(s2, off);
                }
                if (n15 == 0) {
                    int cl = mt * 16 + q * 4 + reg;
                    sbp[wv * 64 + cl * 2] = s;
                    sbp[wv * 64 + cl * 2 + 1] = s2;
                }
            }
        __syncthreads();
        if (t < 32) {
            float s = 0.f, s2 = 0.f;
            #pragma unroll
            for (int w = 0; w < 4; w++) { s += sbp[w * 64 + t * 2]; s2 += sbp[w * 64 + t * 2 + 1]; }
            atomicAdd(&part1[((co0 + t) << 3) + n].x, s);
            atomicAdd(&part1[((co0 + t) << 3) + n].y, s2);
        }
    }
}

// ---------------------------------------------------------------------------
// MFMA conv3x3 (pad=1). Weights read DIRECTLY from global (L2-resident,
// reused 256x per coq) -- no sw LDS stage. LDS 59->38.5 KB => 4 blocks/CU
// (was 2). Same pattern verified on conv1 in rounds 6-7. BN partial stats
// fused into epilogue. (Used only for conv2.)
template<int CIN, int COG, int ROWS, int WPAD, int NCOQ>
__global__ __launch_bounds__(256) void k_conv3(const unsigned short* __restrict__ xb,
                                               const unsigned short* __restrict__ wb,
                                               const float* __restrict__ bias,
                                               float* __restrict__ y,
                                               float2* __restrict__ part,
                                               int COUT_real) {
    constexpr int CPAD = CIN + 8;
    constexpr int NSLC = (ROWS + 2) * 66;
    constexpr int MT = COG / 16;
    constexpr int NTW = ROWS;
    constexpr int KSTEPS = CIN / 32;
    __shared__ unsigned short sx[NSLC * CPAD];
    __shared__ float sbp[4][COG * 2];

    int bid = blockIdx.x;
    int coq = bid % NCOQ;
    int rp = (bid / NCOQ) % (H_ / ROWS);
    int n = bid / (NCOQ * (H_ / ROWS));
    int h0 = rp * ROWS;
    int co0 = coq * COG;
    int t = threadIdx.x;
    int lane = t & 63, wv = t >> 6;
    int q = lane >> 4, n15 = lane & 15;

    {
        const unsigned int* xg = (const unsigned int*)xb + (size_t)n * HW_ * (CIN / 2);
        unsigned int* sxd = (unsigned int*)sx;
        constexpr int DW = CIN / 2;
        constexpr int DWPT = DW / 8;
        int part_ = t & 7;
        for (int sl = (t >> 3); sl < NSLC; sl += 32) {
            int r = sl / 66, col = sl % 66;
            int hh = h0 - 1 + r, ww = col - 1;
            unsigned int v[DWPT];
            #pragma unroll
            for (int i = 0; i < DWPT; i++) v[i] = 0;
            if (hh >= 0 && hh < H_ && ww >= 0 && ww < W_) {
                const unsigned int* gp = xg + (size_t)(hh * W_ + ww) * DW + part_ * DWPT;
                #pragma unroll
                for (int i = 0; i < DWPT; i++) v[i] = gp[i];
            }
            unsigned int* d = sxd + sl * (CPAD / 2) + part_ * DWPT;
            #pragma unroll
            for (int i = 0; i < DWPT; i++) d[i] = v[i];
        }
    }
    __syncthreads();

    f32x4 acc[NTW][MT];
    #pragma unroll
    for (int a = 0; a < NTW; a++)
        #pragma unroll
        for (int m = 0; m < MT; m++) acc[a][m] = (f32x4){0.f, 0.f, 0.f, 0.f};

    #pragma unroll
    for (int s = 0; s < 9; s++) {
        int dy = s / 3, dx = s % 3;
        #pragma unroll
        for (int kc = 0; kc < KSTEPS; kc++) {
            int ci0 = kc * 32;
            short8 bfr[NTW];
            #pragma unroll
            for (int ntl = 0; ntl < NTW; ntl++) {
                int nt = wv * NTW + ntl;
                int r_out = nt >> 2, col0 = (nt & 3) * 16;
                bfr[ntl] = *(const short8*)(sx + ((r_out + dy) * 66 + col0 + n15 + dx) * CPAD + ci0 + q * 8);
            }
            #pragma unroll
            for (int mt = 0; mt < MT; mt++) {
                // A-fragment straight from global: wb[(s*WPAD+co)*CIN + ci]
                short8 afr = *(const short8*)(wb + ((size_t)s * WPAD + co0 + mt * 16 + n15) * CIN + ci0 + q * 8);
                #pragma unroll
                for (int ntl = 0; ntl < NTW; ntl++)
                    acc[ntl][mt] = __builtin_amdgcn_mfma_f32_16x16x32_bf16(afr, bfr[ntl], acc[ntl][mt], 0, 0, 0);
            }
        }
    }

    float sacc[MT][4], sacc2[MT][4];
    #pragma unroll
    for (int mt = 0; mt < MT; mt++)
        #pragma unroll
        for (int reg = 0; reg < 4; reg++) { sacc[mt][reg] = 0.f; sacc2[mt][reg] = 0.f; }

    #pragma unroll
    for (int ntl = 0; ntl < NTW; ntl++) {
        int nt = wv * NTW + ntl;
        int h = h0 + (nt >> 2), wcol = (nt & 3) * 16 + n15;
        #pragma unroll
        for (int mt = 0; mt < MT; mt++) {
            #pragma unroll
            for (int reg = 0; reg < 4; reg++) {
                int co = co0 + mt * 16 + q * 4 + reg;
                if (co < COUT_real) {
                    float v = acc[ntl][mt][reg] + bias[co];
                    y[(((size_t)n * COUT_real + co) << 12) + h * W_ + wcol] = v;
                    sacc[mt][reg] += v;
                    sacc2[mt][reg] += v * v;
                }
            }
        }
    }

    #pragma unroll
    for (int mt = 0; mt < MT; mt++)
        #pragma unroll
        for (int reg = 0; reg < 4; reg++) {
            float s = sacc[mt][reg], s2 = sacc2[mt][reg];
            #pragma unroll
            for (int off = 1; off < 16; off <<= 1) {
                s += __shfl_xor(s, off);
                s2 += __shfl_xor(s2, off);
            }
            if (n15 == 0) {
                int cl = mt * 16 + q * 4 + reg;
                sbp[wv][cl * 2] = s;
                sbp[wv][cl * 2 + 1] = s2;
            }
        }
    __syncthreads();
    if (t < COG) {
        float s = 0.f, s2 = 0.f;
        #pragma unroll
        for (int w2 = 0; w2 < 4; w2++) { s += sbp[w2][t * 2]; s2 += sbp[w2][t * 2 + 1]; }
        int co = co0 + t;
        if (co < COUT_real) {
            atomicAdd(&part[(co << 3) + n].x, s);
            atomicAdd(&part[(co << 3) + n].y, s2);
        }
    }
}

// ---------------------------------------------------------------------------
// y1 NCHW f32 -> tanh(bn) -> y1b NHWC bf16
__global__ __launch_bounds__(256) void k_bntr(const float* __restrict__ y1,
                                              const float2* __restrict__ part,
                                              const float* __restrict__ g,
                                              const float* __restrict__ bb,
                                              unsigned short* __restrict__ y1b) {
    __shared__ unsigned short sT[64 * 68];
    __shared__ float scs[INTER_], shs[INTER_];
    int bid = blockIdx.x, t = threadIdx.x;
    int n = bid >> 6, hw0 = (bid << 6) & 4095;
    if (t < INTER_) {
        float s = 0.f, s2 = 0.f;
        #pragma unroll
        for (int j = 0; j < 8; j++) { float2 p = part[t * 8 + j]; s += p.x; s2 += p.y; }
        float mu = s / (float)NHW_, var = s2 / (float)NHW_ - mu * mu;
        float sc = g[t] * rsqrtf(var + 1e-5f);
        scs[t] = sc; shs[t] = bb[t] - mu * sc;
    }
    __syncthreads();
    for (int i = t; i < 4096; i += 256) {
        int c = i >> 6, px = i & 63;
        float v = y1[(((size_t)n * INTER_ + c) << 12) + hw0 + px];
        sT[px * 68 + c] = f2bf(tanhf(v * scs[c] + shs[c]));
    }
    __syncthreads();
    unsigned int* yd = (unsigned int*)y1b;
    for (int i = t; i < 2048; i += 256) {
        int px = i >> 5, cw = i & 31;
        unsigned int lo = sT[px * 68 + cw * 2], hi = sT[px * 68 + cw * 2 + 1];
        yd[(((size_t)n << 12) + hw0 + px) * 32 + cw] = lo | (hi << 16);
    }
}

// ---------------------------------------------------------------------------
// Fused tail: hoisted P2 loads, packed-fp32 phase 2, split-bf16 MFMA proj.
#define YPAD_ 97
__global__ __launch_bounds__(256) void k_ytail(const float* __restrict__ y2,
                                               const float2* __restrict__ part,
                                               const float* __restrict__ g,
                                               const float* __restrict__ bb,
                                               const unsigned int* __restrict__ P2,
                                               const unsigned short* __restrict__ wbp,
                                               const float* __restrict__ out_b,
                                               float* __restrict__ out) {
    __shared__ float scs[BC_], shs[BC_];
    __shared__ float cfs[BC_][32];
    __shared__ unsigned int sYh[32 * YPAD_];
    __shared__ unsigned int sYl[32 * YPAD_];

    int bid = blockIdx.x;
    int n = bid >> 7, px0 = (bid & 127) << 5;
    int t = threadIdx.x;

    int px = t & 31, cg = t >> 5;
    unsigned int u[4][9];
    {
        const unsigned int* Pb = P2 + (((size_t)n * P2CH_) << 12) + px0 + px;
        #pragma unroll
        for (int cc = 0; cc < 4; cc++) {
            int c = cg * 4 + cc;
            #pragma unroll
            for (int tp = 0; tp < 9; tp++)
                u[cc][tp] = Pb[(size_t)(tp * 32 + c) << 12];
        }
    }

    if (t < BC_) {
        float s = 0.f, s2 = 0.f;
        #pragma unroll
        for (int j = 0; j < 8; j++) { float2 p = part[t * 8 + j]; s += p.x; s2 += p.y; }
        float mu = s / (float)NHW_, var = s2 / (float)NHW_ - mu * mu;
        float sc = g[t] * rsqrtf(var + 1e-5f);
        scs[t] = sc; shs[t] = bb[t] - mu * sc;
    }
    __syncthreads();

    for (int i = t; i < BC_ * 32; i += 256) {
        int ch = i >> 5, pxx = i & 31;
        float v = y2[(((size_t)n * BC_ + ch) << 12) + px0 + pxx];
        cfs[ch][pxx] = tanhf(v * scs[ch] + shs[ch]);
    }
    __syncthreads();

    {
        f32x2 pv2[2][TB_];
        #pragma unroll
        for (int j = 0; j < 2; j++)
            #pragma unroll
            for (int tp = 0; tp < 9; tp++) {
                pv2[j][2 * tp].x     = __uint_as_float(u[2 * j][tp] << 16);
                pv2[j][2 * tp].y     = __uint_as_float(u[2 * j + 1][tp] << 16);
                pv2[j][2 * tp + 1].x = __uint_as_float(u[2 * j][tp] & 0xffff0000u);
                pv2[j][2 * tp + 1].y = __uint_as_float(u[2 * j + 1][tp] & 0xffff0000u);
            }
        f32x2 ym2[2][NB_];
        #pragma unroll
        for (int j = 0; j < 2; j++)
            #pragma unroll
            for (int m = 0; m < NB_; m++) ym2[j][m] = (f32x2){0.f, 0.f};
        #pragma unroll
        for (int m = 0; m < NB_; m++)
            #pragma unroll
            for (int tt = 0; tt < TB_; tt++) {
                float cfv = cfs[m * TB_ + tt][px];
                f32x2 c2 = (f32x2){cfv, cfv};
                ym2[0][m] += c2 * pv2[0][tt];
                ym2[1][m] += c2 * pv2[1][tt];
            }
        #pragma unroll
        for (int j = 0; j < 2; j++) {
            #pragma unroll
            for (int half = 0; half < 2; half++) {
                int c = cg * 4 + 2 * j + half;
                #pragma unroll
                for (int jj = 0; jj < 3; jj++) {
                    float y0 = half ? ym2[j][2 * jj].y     : ym2[j][2 * jj].x;
                    float y1v = half ? ym2[j][2 * jj + 1].y : ym2[j][2 * jj + 1].x;
                    unsigned short h0 = f2bf(y0);
                    unsigned short h1 = f2bf(y1v);
                    unsigned short l0 = f2bf(y0 - bf2f(h0));
                    unsigned short l1 = f2bf(y1v - bf2f(h1));
                    sYh[px * YPAD_ + c * 3 + jj] = (unsigned int)h0 | ((unsigned int)h1 << 16);
                    sYl[px * YPAD_ + c * 3 + jj] = (unsigned int)l0 | ((unsigned int)l1 << 16);
                }
            }
        }
    }
    __syncthreads();

    int lane = t & 63, wv = t >> 6;
    int q = lane >> 4, n15 = lane & 15;
    f32x4 acc[2];
    acc[0] = (f32x4){0.f, 0.f, 0.f, 0.f};
    acc[1] = (f32x4){0.f, 0.f, 0.f, 0.f};
    #pragma unroll
    for (int ks = 0; ks < 6; ks++) {
        short8 ah = *(const short8*)(wbp + (wv * 16 + n15) * DDIM_ + ks * 32 + q * 8);
        short8 al = *(const short8*)(wbp + OUT_ * DDIM_ + (wv * 16 + n15) * DDIM_ + ks * 32 + q * 8);
        #pragma unroll
        for (int nt = 0; nt < 2; nt++) {
            short8 bh = frag4(sYh + (nt * 16 + n15) * YPAD_ + ks * 16 + q * 4);
            short8 bl = frag4(sYl + (nt * 16 + n15) * YPAD_ + ks * 16 + q * 4);
            acc[nt] = __builtin_amdgcn_mfma_f32_16x16x32_bf16(ah, bh, acc[nt], 0, 0, 0);
            acc[nt] = __builtin_amdgcn_mfma_f32_16x16x32_bf16(ah, bl, acc[nt], 0, 0, 0);
            acc[nt] = __builtin_amdgcn_mfma_f32_16x16x32_bf16(al, bh, acc[nt], 0, 0, 0);
        }
    }
    #pragma unroll
    for (int nt = 0; nt < 2; nt++)
        #pragma unroll
        for (int reg = 0; reg < 4; reg++) {
            int o = wv * 16 + q * 4 + reg;
            out[(((size_t)n * OUT_ + o) << 12) + px0 + nt * 16 + n15] = acc[nt][reg] + out_b[o];
        }
}

extern "C" void kernel_launch(void* const* d_in, const int* in_sizes, int n_in,
                              void* d_out, int out_size, void* d_ws, size_t ws_size,
                              hipStream_t stream) {
    const float* x       = (const float*)d_in[0];
    const float* conv1_w = (const float*)d_in[1];
    const float* conv1_b = (const float*)d_in[2];
    const float* bn1_g   = (const float*)d_in[3];
    const float* bn1_b   = (const float*)d_in[4];
    const float* conv2_w = (const float*)d_in[5];
    const float* conv2_b = (const float*)d_in[6];
    const float* bn2_g   = (const float*)d_in[7];
    const float* bn2_b   = (const float*)d_in[8];
    const float* bases   = (const float*)d_in[9];
    const float* out_w   = (const float*)d_in[10];
    const float* out_b   = (const float*)d_in[11];
    float* out = (float*)d_out;

    float* y1  = (float*)d_ws;                       // 2,097,152 f32
    float* y2  = y1 + (size_t)N_ * INTER_ * HW_;     // 3,538,944 f32
    unsigned int* P2 = (unsigned int*)(y2 + (size_t)N_ * BC_ * HW_); // 9,437,184 dw
    unsigned short* xb  = (unsigned short*)(P2 + (size_t)N_ * P2CH_ * HW_); // (unused, layout kept)
    unsigned short* y1b = xb + (size_t)NHW_ * C_;    // 2,097,152
    unsigned short* wb1 = y1b + (size_t)NHW_ * INTER_; // 18,432
    unsigned short* wb2 = wb1 + 9 * 64 * 32;         // 73,728
    unsigned short* wbp = wb2 + 9 * 128 * 64;        // 24,576 (hi + lo)
    float2* part1 = (float2*)(wbp + 2 * OUT_ * DDIM_); // 64*8
    float2* part2 = part1 + INTER_ * 8;              // 108*8
    unsigned short* basesM = (unsigned short*)(part2 + BC_ * 8); // 2048 bf16

    k_prep<<<410, 256, 0, stream>>>(conv1_w, conv2_w, out_w, bases,
                                    wb1, wb2, wbp, basesM, (float*)part1);

    k_front<<<2048, 256, 0, stream>>>(x, basesM, wb1, conv1_b, P2, y1, part1);

    k_bntr<<<512, 256, 0, stream>>>(y1, part1, bn1_g, bn1_b, y1b);

    k_conv3<INTER_, 16, 2, 128, 7><<<N_ * 32 * 7, 256, 0, stream>>>(
        y1b, wb2, conv2_b, y2, part2, BC_);

    k_ytail<<<1024, 256, 0, stream>>>(y2, (const float2*)part2, bn2_g, bn2_b,
                                      P2, wbp, out_b, out);
}

// Round 17
// 183.647 us; speedup vs baseline: 1.0164x; 1.0164x over previous
//
#include <hip/hip_runtime.h>
#include <hip/hip_bf16.h>

#define N_ 8
#define C_ 32
#define H_ 64
#define W_ 64
#define HW_ (H_*W_)
#define NHW_ (N_*HW_)
#define INTER_ 64
#define BC_ 108
#define KS_ 7
#define K2_ (KS_*KS_)
#define NB_ 6
#define TB_ 18
#define OUT_ 64
#define DDIM_ (C_*NB_)   // 192
#define P2CH_ 288        // 9 tp-pairs * 32 c

typedef __attribute__((ext_vector_type(8))) short short8;
typedef __attribute__((ext_vector_type(4))) float f32x4;
typedef __attribute__((ext_vector_type(2))) float f32x2;

__device__ __forceinline__ unsigned short f2bf(float f) {
    union { float f; unsigned u; } v; v.f = f;
    unsigned r = v.u + 0x7fffu + ((v.u >> 16) & 1u);
    return (unsigned short)(r >> 16);
}
__device__ __forceinline__ float bf2f(unsigned short h) {
    return __uint_as_float((unsigned int)h << 16);
}

__device__ __forceinline__ short8 frag4(const unsigned int* p) {
    union { unsigned int u[4]; short8 s; } v;
    v.u[0] = p[0]; v.u[1] = p[1]; v.u[2] = p[2]; v.u[3] = p[3];
    return v.s;
}

// ---------------------------------------------------------------------------
// k_prep: one-time weight conversions + basesM packing + BN-partial zeroing.
// basesM: A-fragment table for the MFMA pconv, layout [mt][ks][lane][j] bf16.
// k' = ky*8 + kx (K padded 49->64): lane(q,n15) holds A[m=n15][k=q*8+j] of
// k-step ks -> ky = ks*4+q, kx = j; zero at tp2>=18 | ky>=7 | kx>=7.
__global__ __launch_bounds__(256) void k_prep(const float* __restrict__ w1,
                                              const float* __restrict__ w2,
                                              const float* __restrict__ ow,
                                              const float* __restrict__ bases,
                                              unsigned short* __restrict__ wb1,
                                              unsigned short* __restrict__ wb2,
                                              unsigned short* __restrict__ wbp,
                                              unsigned short* __restrict__ basesM,
                                              float* __restrict__ pz) {
    int bid = blockIdx.x, t = threadIdx.x;
    if (bid < 72) {
        int i = bid * 256 + t;                // < 18432 = 9*64*32
        int ci = i & 31, co = (i >> 5) & 63, s = i >> 11;
        wb1[i] = f2bf(w1[((co << 5) + ci) * 9 + s]);   // wb1[s*2048 + co*32 + ci]
    } else if (bid < 360) {
        int i = (bid - 72) * 256 + t;         // < 73728 = 9*128*64
        int ci = i & 63, co = (i >> 6) & 127, s = i >> 13;
        unsigned short v = 0;
        if (co < BC_) v = f2bf(w2[((co << 6) + ci) * 9 + s]);
        wb2[i] = v;
    } else if (bid < 408) {
        int i = (bid - 360) * 256 + t;        // < 12288 = 64*192
        if (i < OUT_ * DDIM_) {
            float v = ow[i];
            unsigned short hi = f2bf(v);
            wbp[i] = hi;
            wbp[OUT_ * DDIM_ + i] = f2bf(v - bf2f(hi));
        }
    } else if (bid == 408) {
        // zero part1|part2: (INTER_+BC_)*8 float2 = 2752 floats
        for (int i = t; i < (INTER_ + BC_) * 8 * 2; i += 256) pz[i] = 0.f;
    } else {
        // basesM: 2mt * 2ks * 64lane * 8j = 2048 bf16
        for (int i = t; i < 2048; i += 256) {
            int j = i & 7, lane = (i >> 3) & 63, sk = (i >> 9) & 1, mt = i >> 10;
            int q = lane >> 4, n15 = lane & 15;
            int tp2 = mt * 16 + n15;
            int ky = sk * 4 + q, kx = j;
            unsigned short v = 0;
            if (tp2 < TB_ && ky < 7 && kx < 7)
                v = f2bf(bases[tp2 * K2_ + ky * 7 + kx]);
            basesM[i] = v;
        }
    }
}

// ---------------------------------------------------------------------------
// k_front: horizontal fusion of (pconv-MFMA | conv1-direct), 1:1 interleave.
// pconv as MFMA GEMM: P[tp2][px] = sum_k bases[tp2][k] * patch[k][px],
// k' = ky*8+kx. B-col n15 -> pixels {2n15, 2n15+1, 2n15+32, 2n15+33}: the
// aligned u32 window d[0..4] (elements 2n15..2n15+9, 4B-aligned) yields f0
// directly and f1 by 16-bit funnel shift (v_alignbit). Adjacent pixel pairs
// give 8B-coalesced dwordx2 P2 stores.
__global__ __launch_bounds__(256) void k_front(const float* __restrict__ x,
                                               const unsigned short* __restrict__ basesM,
                                               const unsigned short* __restrict__ wb1,
                                               const float* __restrict__ b1,
                                               unsigned int* __restrict__ P2,
                                               float* __restrict__ y1,
                                               float2* __restrict__ part1) {
    __shared__ __align__(16) char smem[16896];
    int bid = blockIdx.x, t = threadIdx.x;
    int g = bid >> 1, fr = bid & 1;      // 1:1 interleave

    if (fr == 0) {
        // ---- pconv family (MFMA): pid -> (n, c, rg) ----
        unsigned short* xt = (unsigned short*)smem;   // [23][72] bf16, col shift 3
        int rg = g & 3;
        int c  = (g >> 2) & 31;
        int n  = g >> 7;
        int h0 = rg << 4;
        int lane = t & 63, wv = t >> 6;
        int q = lane >> 4, n15 = lane & 15;

        const float* xc = x + (((size_t)n * C_ + c) << 12);
        for (int i = t; i < 23 * 72; i += 256) {
            int r = i / 72, cl = i % 72;
            int gr = h0 - 3 + r, gc = cl - 3;
            float v = 0.f;
            if (r < 22 && gr >= 0 && gr < H_ && gc >= 0 && gc < W_)
                v = xc[(gr << 6) + gc];
            xt[i] = f2bf(v);
        }
        __syncthreads();

        short8 afr[2][2];
        #pragma unroll
        for (int mt = 0; mt < 2; mt++)
            #pragma unroll
            for (int sk = 0; sk < 2; sk++)
                afr[mt][sk] = *(const short8*)(basesM + ((mt * 2 + sk) * 64 + lane) * 8);

        #pragma unroll 1
        for (int rr = 0; rr < 4; rr++) {
            int hrow = wv * 4 + rr;          // 0..15
            int h = h0 + hrow;
            f32x4 acc[4][2];                 // [cc: px 2n15,2n15+1,2n15+32,2n15+33][mt]
            #pragma unroll
            for (int cc = 0; cc < 4; cc++) {
                acc[cc][0] = (f32x4){0.f, 0.f, 0.f, 0.f};
                acc[cc][1] = (f32x4){0.f, 0.f, 0.f, 0.f};
            }
            #pragma unroll
            for (int sk = 0; sk < 2; sk++) {
                // aligned u32 window: elements 2n15.. (u32 index row*36+n15)
                const unsigned int* rp32 = (const unsigned int*)xt +
                                           (hrow + sk * 4 + q) * 36 + n15;
                unsigned int d0 = rp32[0], d1 = rp32[1], d2 = rp32[2],
                             d3 = rp32[3], d4 = rp32[4];
                unsigned int e0 = rp32[16], e1 = rp32[17], e2 = rp32[18],
                             e3 = rp32[19], e4 = rp32[20];
                union { unsigned int u[4]; short8 s; } f0, f1, f2v, f3v;
                f0.u[0] = d0; f0.u[1] = d1; f0.u[2] = d2; f0.u[3] = d3;
                f1.u[0] = (d0 >> 16) | (d1 << 16);
                f1.u[1] = (d1 >> 16) | (d2 << 16);
                f1.u[2] = (d2 >> 16) | (d3 << 16);
                f1.u[3] = (d3 >> 16) | (d4 << 16);
                f2v.u[0] = e0; f2v.u[1] = e1; f2v.u[2] = e2; f2v.u[3] = e3;
                f3v.u[0] = (e0 >> 16) | (e1 << 16);
                f3v.u[1] = (e1 >> 16) | (e2 << 16);
                f3v.u[2] = (e2 >> 16) | (e3 << 16);
                f3v.u[3] = (e3 >> 16) | (e4 << 16);
                acc[0][0] = __builtin_amdgcn_mfma_f32_16x16x32_bf16(afr[0][sk], f0.s, acc[0][0], 0, 0, 0);
                acc[0][1] = __builtin_amdgcn_mfma_f32_16x16x32_bf16(afr[1][sk], f0.s, acc[0][1], 0, 0, 0);
                acc[1][0] = __builtin_amdgcn_mfma_f32_16x16x32_bf16(afr[0][sk], f1.s, acc[1][0], 0, 0, 0);
                acc[1][1] = __builtin_amdgcn_mfma_f32_16x16x32_bf16(afr[1][sk], f1.s, acc[1][1], 0, 0, 0);
                acc[2][0] = __builtin_amdgcn_mfma_f32_16x16x32_bf16(afr[0][sk], f2v.s, acc[2][0], 0, 0, 0);
                acc[2][1] = __builtin_amdgcn_mfma_f32_16x16x32_bf16(afr[1][sk], f2v.s, acc[2][1], 0, 0, 0);
                acc[3][0] = __builtin_amdgcn_mfma_f32_16x16x32_bf16(afr[0][sk], f3v.s, acc[3][0], 0, 0, 0);
                acc[3][1] = __builtin_amdgcn_mfma_f32_16x16x32_bf16(afr[1][sk], f3v.s, acc[3][1], 0, 0, 0);
            }
            // stores: D row m=q*4+reg -> tp2; pairs (reg0,reg1)->tp=2q,
            // (reg2,reg3)->tp=2q+1; mt=1 q==0 -> tp=8. Adjacent px pair ->
            // one 8B store at col 2n15 (+32 for pp=1).
            size_t pb = ((size_t)n * P2CH_) << 12;
            #pragma unroll
            for (int pp = 0; pp < 2; pp++) {
                int ccb = pp * 2;
                int colb = 2 * n15 + pp * 32;
                unsigned int lo0 = (unsigned int)f2bf(acc[ccb][0][0]) |
                                   ((unsigned int)f2bf(acc[ccb][0][1]) << 16);
                unsigned int hi0 = (unsigned int)f2bf(acc[ccb + 1][0][0]) |
                                   ((unsigned int)f2bf(acc[ccb + 1][0][1]) << 16);
                unsigned int lo1 = (unsigned int)f2bf(acc[ccb][0][2]) |
                                   ((unsigned int)f2bf(acc[ccb][0][3]) << 16);
                unsigned int hi1 = (unsigned int)f2bf(acc[ccb + 1][0][2]) |
                                   ((unsigned int)f2bf(acc[ccb + 1][0][3]) << 16);
                *(unsigned long long*)&P2[pb + (((size_t)(2 * q) * 32 + c) << 12) + (h << 6) + colb] =
                    (unsigned long long)lo0 | ((unsigned long long)hi0 << 32);
                *(unsigned long long*)&P2[pb + (((size_t)(2 * q + 1) * 32 + c) << 12) + (h << 6) + colb] =
                    (unsigned long long)lo1 | ((unsigned long long)hi1 << 32);
                if (q == 0) {
                    unsigned int lo8 = (unsigned int)f2bf(acc[ccb][1][0]) |
                                       ((unsigned int)f2bf(acc[ccb][1][1]) << 16);
                    unsigned int hi8 = (unsigned int)f2bf(acc[ccb + 1][1][0]) |
                                       ((unsigned int)f2bf(acc[ccb + 1][1][1]) << 16);
                    *(unsigned long long*)&P2[pb + (((size_t)8 * 32 + c) << 12) + (h << 6) + colb] =
                        (unsigned long long)lo8 | ((unsigned long long)hi8 << 32);
                }
            }
        }
    } else {
        // ---- conv1 family: COG=32, ROWS=1, weights from global wb1 ----
        // LDS carve: sx1[198][40] bf16 (15840B) | sbp[4][64] f32 (1024B)
        unsigned short* sx1 = (unsigned short*)smem;
        float* sbp = (float*)(sx1 + 198 * 40);   // offset 15840 (16-aligned)

        int cid = g;                   // 0..1023
        int n = cid >> 7;              // 0..7
        int rem = cid & 127;
        int co0 = (rem & 1) << 5;      // 2 co-halves of 32
        int h0 = rem >> 1;             // 64 rows
        int lane = t & 63, wv = t >> 6;
        int q = lane >> 4, n15 = lane & 15;

        // stage x tile: rows h0-1..h0+1, cols 1..64 (x cols 0..63), 32 ch, bf16
        for (int e = t; e < 1536; e += 256) {
            int c = e & 31, rc4 = e >> 5;        // rc4 in 0..47
            int r = rc4 >> 4, cq = rc4 & 15;     // r 0..2, cq 0..15
            int hh = h0 - 1 + r;
            bool rok = (hh >= 0 && hh < H_);
            float4 v = {0.f, 0.f, 0.f, 0.f};
            if (rok) v = *(const float4*)(x + (((size_t)n * C_ + c) << 12) + (hh << 6) + cq * 4);
            unsigned short* d = sx1 + (r * 66 + 1 + cq * 4) * 40 + c;
            d[0]   = f2bf(v.x);
            d[40]  = f2bf(v.y);
            d[80]  = f2bf(v.z);
            d[120] = f2bf(v.w);
        }
        // border zeros: cols 0 and 65, 3 rows x 32 channels
        if (t < 96) {
            int c = t & 31, r = t >> 5;
            sx1[(r * 66 + 0) * 40 + c] = 0;
            sx1[(r * 66 + 65) * 40 + c] = 0;
        }
        __syncthreads();

        f32x4 acc[2];
        acc[0] = (f32x4){0.f, 0.f, 0.f, 0.f};
        acc[1] = (f32x4){0.f, 0.f, 0.f, 0.f};
        #pragma unroll
        for (int s = 0; s < 9; s++) {
            int dy = s / 3, dx = s % 3;
            short8 bfr = *(const short8*)(sx1 + (dy * 66 + wv * 16 + n15 + dx) * 40 + q * 8);
            #pragma unroll
            for (int mt = 0; mt < 2; mt++) {
                short8 afr = *(const short8*)(wb1 + s * 2048 + (co0 + mt * 16 + n15) * 32 + q * 8);
                acc[mt] = __builtin_amdgcn_mfma_f32_16x16x32_bf16(afr, bfr, acc[mt], 0, 0, 0);
            }
        }

        // epilogue: store y1 + BN1 partial stats
        int wcol = wv * 16 + n15;
        float sa[2][4], sa2[2][4];
        #pragma unroll
        for (int mt = 0; mt < 2; mt++)
            #pragma unroll
            for (int reg = 0; reg < 4; reg++) {
                int co = co0 + mt * 16 + q * 4 + reg;
                float v = acc[mt][reg] + b1[co];
                y1[(((size_t)n * INTER_ + co) << 12) + (h0 << 6) + wcol] = v;
                sa[mt][reg] = v; sa2[mt][reg] = v * v;
            }
        #pragma unroll
        for (int mt = 0; mt < 2; mt++)
            #pragma unroll
            for (int reg = 0; reg < 4; reg++) {
                float s = sa[mt][reg], s2 = sa2[mt][reg];
                #pragma unroll
                for (int off = 1; off < 16; off <<= 1) {
                    s += __shfl_xor(s, off);
                    s2 += __shfl_xor(s2, off);
                }
                if (n15 == 0) {
                    int cl = mt * 16 + q * 4 + reg;
                    sbp[wv * 64 + cl * 2] = s;
                    sbp[wv * 64 + cl * 2 + 1] = s2;
                }
            }
        __syncthreads();
        if (t < 32) {
            float s = 0.f, s2 = 0.f;
            #pragma unroll
            for (int w = 0; w < 4; w++) { s += sbp[w * 64 + t * 2]; s2 += sbp[w * 64 + t * 2 + 1]; }
            atomicAdd(&part1[((co0 + t) << 3) + n].x, s);
            atomicAdd(&part1[((co0 + t) << 3) + n].y, s2);
        }
    }
}

// ---------------------------------------------------------------------------
// MFMA conv3x3 (pad=1), stage-once (weights in LDS -- the verified-fastest
// configuration; direct-global weights measured +1.8us in round 16).
// BN partial stats fused into epilogue. (Used only for conv2.)
template<int CIN, int COG, int ROWS, int WPAD, int NCOQ>
__global__ __launch_bounds__(256) void k_conv3(const unsigned short* __restrict__ xb,
                                               const unsigned short* __restrict__ wb,
                                               const float* __restrict__ bias,
                                               float* __restrict__ y,
                                               float2* __restrict__ part,
                                               int COUT_real) {
    constexpr int CPAD = CIN + 8;
    constexpr int NSLC = (ROWS + 2) * 66;
    constexpr int MT = COG / 16;
    constexpr int NTW = ROWS;
    constexpr int KSTEPS = CIN / 32;
    __shared__ unsigned short sx[NSLC * CPAD];
    __shared__ unsigned short sw[9 * COG * CPAD];
    __shared__ float sbp[4][COG * 2];

    int bid = blockIdx.x;
    int coq = bid % NCOQ;
    int rp = (bid / NCOQ) % (H_ / ROWS);
    int n = bid / (NCOQ * (H_ / ROWS));
    int h0 = rp * ROWS;
    int co0 = coq * COG;
    int t = threadIdx.x;
    int lane = t & 63, wv = t >> 6;
    int q = lane >> 4, n15 = lane & 15;

    {
        const unsigned int* xg = (const unsigned int*)xb + (size_t)n * HW_ * (CIN / 2);
        unsigned int* sxd = (unsigned int*)sx;
        constexpr int DW = CIN / 2;
        constexpr int DWPT = DW / 8;
        int part_ = t & 7;
        for (int sl = (t >> 3); sl < NSLC; sl += 32) {
            int r = sl / 66, col = sl % 66;
            int hh = h0 - 1 + r, ww = col - 1;
            unsigned int v[DWPT];
            #pragma unroll
            for (int i = 0; i < DWPT; i++) v[i] = 0;
            if (hh >= 0 && hh < H_ && ww >= 0 && ww < W_) {
                const unsigned int* gp = xg + (size_t)(hh * W_ + ww) * DW + part_ * DWPT;
                #pragma unroll
                for (int i = 0; i < DWPT; i++) v[i] = gp[i];
            }
            unsigned int* d = sxd + sl * (CPAD / 2) + part_ * DWPT;
            #pragma unroll
            for (int i = 0; i < DWPT; i++) d[i] = v[i];
        }
    }
    {
        const unsigned int* wg = (const unsigned int*)wb;
        unsigned int* swd = (unsigned int*)sw;
        constexpr int TOT = 9 * COG * (CIN / 2);
        for (int e = t; e < TOT; e += 256) {
            int s_co = e / (CIN / 2), cw = e % (CIN / 2);
            int s = s_co / COG, co = s_co % COG;
            swd[s_co * (CPAD / 2) + cw] = wg[((size_t)s * WPAD + co0 + co) * (CIN / 2) + cw];
        }
    }
    __syncthreads();

    f32x4 acc[NTW][MT];
    #pragma unroll
    for (int a = 0; a < NTW; a++)
        #pragma unroll
        for (int m = 0; m < MT; m++) acc[a][m] = (f32x4){0.f, 0.f, 0.f, 0.f};

    #pragma unroll
    for (int s = 0; s < 9; s++) {
        int dy = s / 3, dx = s % 3;
        #pragma unroll
        for (int kc = 0; kc < KSTEPS; kc++) {
            int ci0 = kc * 32;
            short8 bfr[NTW];
            #pragma unroll
            for (int ntl = 0; ntl < NTW; ntl++) {
                int nt = wv * NTW + ntl;
                int r_out = nt >> 2, col0 = (nt & 3) * 16;
                bfr[ntl] = *(const short8*)(sx + ((r_out + dy) * 66 + col0 + n15 + dx) * CPAD + ci0 + q * 8);
            }
            #pragma unroll
            for (int mt = 0; mt < MT; mt++) {
                short8 afr = *(const short8*)(sw + ((s * COG) + mt * 16 + n15) * CPAD + ci0 + q * 8);
                #pragma unroll
                for (int ntl = 0; ntl < NTW; ntl++)
                    acc[ntl][mt] = __builtin_amdgcn_mfma_f32_16x16x32_bf16(afr, bfr[ntl], acc[ntl][mt], 0, 0, 0);
            }
        }
    }

    float sacc[MT][4], sacc2[MT][4];
    #pragma unroll
    for (int mt = 0; mt < MT; mt++)
        #pragma unroll
        for (int reg = 0; reg < 4; reg++) { sacc[mt][reg] = 0.f; sacc2[mt][reg] = 0.f; }

    #pragma unroll
    for (int ntl = 0; ntl < NTW; ntl++) {
        int nt = wv * NTW + ntl;
        int h = h0 + (nt >> 2), wcol = (nt & 3) * 16 + n15;
        #pragma unroll
        for (int mt = 0; mt < MT; mt++) {
            #pragma unroll
            for (int reg = 0; reg < 4; reg++) {
                int co = co0 + mt * 16 + q * 4 + reg;
                if (co < COUT_real) {
                    float v = acc[ntl][mt][reg] + bias[co];
                    y[(((size_t)n * COUT_real + co) << 12) + h * W_ + wcol] = v;
                    sacc[mt][reg] += v;
                    sacc2[mt][reg] += v * v;
                }
            }
        }
    }

    #pragma unroll
    for (int mt = 0; mt < MT; mt++)
        #pragma unroll
        for (int reg = 0; reg < 4; reg++) {
            float s = sacc[mt][reg], s2 = sacc2[mt][reg];
            #pragma unroll
            for (int off = 1; off < 16; off <<= 1) {
                s += __shfl_xor(s, off);
                s2 += __shfl_xor(s2, off);
            }
            if (n15 == 0) {
                int cl = mt * 16 + q * 4 + reg;
                sbp[wv][cl * 2] = s;
                sbp[wv][cl * 2 + 1] = s2;
            }
        }
    __syncthreads();
    if (t < COG) {
        float s = 0.f, s2 = 0.f;
        #pragma unroll
        for (int w2 = 0; w2 < 4; w2++) { s += sbp[w2][t * 2]; s2 += sbp[w2][t * 2 + 1]; }
        int co = co0 + t;
        if (co < COUT_real) {
            atomicAdd(&part[(co << 3) + n].x, s);
            atomicAdd(&part[(co << 3) + n].y, s2);
        }
    }
}

// ---------------------------------------------------------------------------
// y1 NCHW f32 -> tanh(bn) -> y1b NHWC bf16
__global__ __launch_bounds__(256) void k_bntr(const float* __restrict__ y1,
                                              const float2* __restrict__ part,
                                              const float* __restrict__ g,
                                              const float* __restrict__ bb,
                                              unsigned short* __restrict__ y1b) {
    __shared__ unsigned short sT[64 * 68];
    __shared__ float scs[INTER_], shs[INTER_];
    int bid = blockIdx.x, t = threadIdx.x;
    int n = bid >> 6, hw0 = (bid << 6) & 4095;
    if (t < INTER_) {
        float s = 0.f, s2 = 0.f;
        #pragma unroll
        for (int j = 0; j < 8; j++) { float2 p = part[t * 8 + j]; s += p.x; s2 += p.y; }
        float mu = s / (float)NHW_, var = s2 / (float)NHW_ - mu * mu;
        float sc = g[t] * rsqrtf(var + 1e-5f);
        scs[t] = sc; shs[t] = bb[t] - mu * sc;
    }
    __syncthreads();
    for (int i = t; i < 4096; i += 256) {
        int c = i >> 6, px = i & 63;
        float v = y1[(((size_t)n * INTER_ + c) << 12) + hw0 + px];
        sT[px * 68 + c] = f2bf(tanhf(v * scs[c] + shs[c]));
    }
    __syncthreads();
    unsigned int* yd = (unsigned int*)y1b;
    for (int i = t; i < 2048; i += 256) {
        int px = i >> 5, cw = i & 31;
        unsigned int lo = sT[px * 68 + cw * 2], hi = sT[px * 68 + cw * 2 + 1];
        yd[(((size_t)n << 12) + hw0 + px) * 32 + cw] = lo | (hi << 16);
    }
}

// ---------------------------------------------------------------------------
// Fused tail: hoisted P2 loads, packed-fp32 phase 2, split-bf16 MFMA proj.
#define YPAD_ 97
__global__ __launch_bounds__(256) void k_ytail(const float* __restrict__ y2,
                                               const float2* __restrict__ part,
                                               const float* __restrict__ g,
                                               const float* __restrict__ bb,
                                               const unsigned int* __restrict__ P2,
                                               const unsigned short* __restrict__ wbp,
                                               const float* __restrict__ out_b,
                                               float* __restrict__ out) {
    __shared__ float scs[BC_], shs[BC_];
    __shared__ float cfs[BC_][32];
    __shared__ unsigned int sYh[32 * YPAD_];
    __shared__ unsigned int sYl[32 * YPAD_];

    int bid = blockIdx.x;
    int n = bid >> 7, px0 = (bid & 127) << 5;
    int t = threadIdx.x;

    int px = t & 31, cg = t >> 5;
    unsigned int u[4][9];
    {
        const unsigned int* Pb = P2 + (((size_t)n * P2CH_) << 12) + px0 + px;
        #pragma unroll
        for (int cc = 0; cc < 4; cc++) {
            int c = cg * 4 + cc;
            #pragma unroll
            for (int tp = 0; tp < 9; tp++)
                u[cc][tp] = Pb[(size_t)(tp * 32 + c) << 12];
        }
    }

    if (t < BC_) {
        float s = 0.f, s2 = 0.f;
        #pragma unroll
        for (int j = 0; j < 8; j++) { float2 p = part[t * 8 + j]; s += p.x; s2 += p.y; }
        float mu = s / (float)NHW_, var = s2 / (float)NHW_ - mu * mu;
        float sc = g[t] * rsqrtf(var + 1e-5f);
        scs[t] = sc; shs[t] = bb[t] - mu * sc;
    }
    __syncthreads();

    for (int i = t; i < BC_ * 32; i += 256) {
        int ch = i >> 5, pxx = i & 31;
        float v = y2[(((size_t)n * BC_ + ch) << 12) + px0 + pxx];
        cfs[ch][pxx] = tanhf(v * scs[ch] + shs[ch]);
    }
    __syncthreads();

    {
        f32x2 pv2[2][TB_];
        #pragma unroll
        for (int j = 0; j < 2; j++)
            #pragma unroll
            for (int tp = 0; tp < 9; tp++) {
                pv2[j][2 * tp].x     = __uint_as_float(u[2 * j][tp] << 16);
                pv2[j][2 * tp].y     = __uint_as_float(u[2 * j + 1][tp] << 16);
                pv2[j][2 * tp + 1].x = __uint_as_float(u[2 * j][tp] & 0xffff0000u);
                pv2[j][2 * tp + 1].y = __uint_as_float(u[2 * j + 1][tp] & 0xffff0000u);
            }
        f32x2 ym2[2][NB_];
        #pragma unroll
        for (int j = 0; j < 2; j++)
            #pragma unroll
            for (int m = 0; m < NB_; m++) ym2[j][m] = (f32x2){0.f, 0.f};
        #pragma unroll
        for (int m = 0; m < NB_; m++)
            #pragma unroll
            for (int tt = 0; tt < TB_; tt++) {
                float cfv = cfs[m * TB_ + tt][px];
                f32x2 c2 = (f32x2){cfv, cfv};
                ym2[0][m] += c2 * pv2[0][tt];
                ym2[1][m] += c2 * pv2[1][tt];
            }
        #pragma unroll
        for (int j = 0; j < 2; j++) {
            #pragma unroll
            for (int half = 0; half < 2; half++) {
                int c = cg * 4 + 2 * j + half;
                #pragma unroll
                for (int jj = 0; jj < 3; jj++) {
                    float y0 = half ? ym2[j][2 * jj].y     : ym2[j][2 * jj].x;
                    float y1v = half ? ym2[j][2 * jj + 1].y : ym2[j][2 * jj + 1].x;
                    unsigned short h0 = f2bf(y0);
                    unsigned short h1 = f2bf(y1v);
                    unsigned short l0 = f2bf(y0 - bf2f(h0));
                    unsigned short l1 = f2bf(y1v - bf2f(h1));
                    sYh[px * YPAD_ + c * 3 + jj] = (unsigned int)h0 | ((unsigned int)h1 << 16);
                    sYl[px * YPAD_ + c * 3 + jj] = (unsigned int)l0 | ((unsigned int)l1 << 16);
                }
            }
        }
    }
    __syncthreads();

    int lane = t & 63, wv = t >> 6;
    int q = lane >> 4, n15 = lane & 15;
    f32x4 acc[2];
    acc[0] = (f32x4){0.f, 0.f, 0.f, 0.f};
    acc[1] = (f32x4){0.f, 0.f, 0.f, 0.f};
    #pragma unroll
    for (int ks = 0; ks < 6; ks++) {
        short8 ah = *(const short8*)(wbp + (wv * 16 + n15) * DDIM_ + ks * 32 + q * 8);
        short8 al = *(const short8*)(wbp + OUT_ * DDIM_ + (wv * 16 + n15) * DDIM_ + ks * 32 + q * 8);
        #pragma unroll
        for (int nt = 0; nt < 2; nt++) {
            short8 bh = frag4(sYh + (nt * 16 + n15) * YPAD_ + ks * 16 + q * 4);
            short8 bl = frag4(sYl + (nt * 16 + n15) * YPAD_ + ks * 16 + q * 4);
            acc[nt] = __builtin_amdgcn_mfma_f32_16x16x32_bf16(ah, bh, acc[nt], 0, 0, 0);
            acc[nt] = __builtin_amdgcn_mfma_f32_16x16x32_bf16(ah, bl, acc[nt], 0, 0, 0);
            acc[nt] = __builtin_amdgcn_mfma_f32_16x16x32_bf16(al, bh, acc[nt], 0, 0, 0);
        }
    }
    #pragma unroll
    for (int nt = 0; nt < 2; nt++)
        #pragma unroll
        for (int reg = 0; reg < 4; reg++) {
            int o = wv * 16 + q * 4 + reg;
            out[(((size_t)n * OUT_ + o) << 12) + px0 + nt * 16 + n15] = acc[nt][reg] + out_b[o];
        }
}

extern "C" void kernel_launch(void* const* d_in, const int* in_sizes, int n_in,
                              void* d_out, int out_size, void* d_ws, size_t ws_size,
                              hipStream_t stream) {
    const float* x       = (const float*)d_in[0];
    const float* conv1_w = (const float*)d_in[1];
    const float* conv1_b = (const float*)d_in[2];
    const float* bn1_g   = (const float*)d_in[3];
    const float* bn1_b   = (const float*)d_in[4];
    const float* conv2_w = (const float*)d_in[5];
    const float* conv2_b = (const float*)d_in[6];
    const float* bn2_g   = (const float*)d_in[7];
    const float* bn2_b   = (const float*)d_in[8];
    const float* bases   = (const float*)d_in[9];
    const float* out_w   = (const float*)d_in[10];
    const float* out_b   = (const float*)d_in[11];
    float* out = (float*)d_out;

    float* y1  = (float*)d_ws;                       // 2,097,152 f32
    float* y2  = y1 + (size_t)N_ * INTER_ * HW_;     // 3,538,944 f32
    unsigned int* P2 = (unsigned int*)(y2 + (size_t)N_ * BC_ * HW_); // 9,437,184 dw
    unsigned short* xb  = (unsigned short*)(P2 + (size_t)N_ * P2CH_ * HW_); // (unused, layout kept)
    unsigned short* y1b = xb + (size_t)NHW_ * C_;    // 2,097,152
    unsigned short* wb1 = y1b + (size_t)NHW_ * INTER_; // 18,432
    unsigned short* wb2 = wb1 + 9 * 64 * 32;         // 73,728
    unsigned short* wbp = wb2 + 9 * 128 * 64;        // 24,576 (hi + lo)
    float2* part1 = (float2*)(wbp + 2 * OUT_ * DDIM_); // 64*8
    float2* part2 = part1 + INTER_ * 8;              // 108*8
    unsigned short* basesM = (unsigned short*)(part2 + BC_ * 8); // 2048 bf16

    k_prep<<<410, 256, 0, stream>>>(conv1_w, conv2_w, out_w, bases,
                                    wb1, wb2, wbp, basesM, (float*)part1);

    k_front<<<2048, 256, 0, stream>>>(x, basesM, wb1, conv1_b, P2, y1, part1);

    k_bntr<<<512, 256, 0, stream>>>(y1, part1, bn1_g, bn1_b, y1b);

    k_conv3<INTER_, 16, 2, 128, 7><<<N_ * 32 * 7, 256, 0, stream>>>(
        y1b, wb2, conv2_b, y2, part2, BC_);

    k_ytail<<<1024, 256, 0, stream>>>(y2, (const float2*)part2, bn2_g, bn2_b,
                                      P2, wbp, out_b, out);
}

// Round 18
// 183.101 us; speedup vs baseline: 1.0194x; 1.0030x over previous
//
#include <hip/hip_runtime.h>
#include <hip/hip_bf16.h>

#define N_ 8
#define C_ 32
#define H_ 64
#define W_ 64
#define HW_ (H_*W_)
#define NHW_ (N_*HW_)
#define INTER_ 64
#define BC_ 108
#define KS_ 7
#define K2_ (KS_*KS_)
#define NB_ 6
#define TB_ 18
#define OUT_ 64
#define DDIM_ (C_*NB_)   // 192
#define P2CH_ 288        // 9 tp-pairs * 32 c

typedef __attribute__((ext_vector_type(8))) short short8;
typedef __attribute__((ext_vector_type(4))) float f32x4;
typedef __attribute__((ext_vector_type(2))) float f32x2;

__device__ __forceinline__ unsigned short f2bf(float f) {
    union { float f; unsigned u; } v; v.f = f;
    unsigned r = v.u + 0x7fffu + ((v.u >> 16) & 1u);
    return (unsigned short)(r >> 16);
}
__device__ __forceinline__ float bf2f(unsigned short h) {
    return __uint_as_float((unsigned int)h << 16);
}

__device__ __forceinline__ short8 frag4(const unsigned int* p) {
    union { unsigned int u[4]; short8 s; } v;
    v.u[0] = p[0]; v.u[1] = p[1]; v.u[2] = p[2]; v.u[3] = p[3];
    return v.s;
}

// ---------------------------------------------------------------------------
// k_prep: one-time weight conversions + basesM packing + BN-partial zeroing.
// basesM: A-fragment table for the MFMA pconv, layout [mt][ks][lane][j] bf16.
// k' = ky*8 + kx (K padded 49->64): lane(q,n15) holds A[m=n15][k=q*8+j] of
// k-step ks -> ky = ks*4+q, kx = j; zero at tp2>=18 | ky>=7 | kx>=7.
__global__ __launch_bounds__(256) void k_prep(const float* __restrict__ w1,
                                              const float* __restrict__ w2,
                                              const float* __restrict__ ow,
                                              const float* __restrict__ bases,
                                              unsigned short* __restrict__ wb1,
                                              unsigned short* __restrict__ wb2,
                                              unsigned short* __restrict__ wbp,
                                              unsigned short* __restrict__ basesM,
                                              float* __restrict__ pz) {
    int bid = blockIdx.x, t = threadIdx.x;
    if (bid < 72) {
        int i = bid * 256 + t;                // < 18432 = 9*64*32
        int ci = i & 31, co = (i >> 5) & 63, s = i >> 11;
        wb1[i] = f2bf(w1[((co << 5) + ci) * 9 + s]);   // wb1[s*2048 + co*32 + ci]
    } else if (bid < 360) {
        int i = (bid - 72) * 256 + t;         // < 73728 = 9*128*64
        int ci = i & 63, co = (i >> 6) & 127, s = i >> 13;
        unsigned short v = 0;
        if (co < BC_) v = f2bf(w2[((co << 6) + ci) * 9 + s]);
        wb2[i] = v;
    } else if (bid < 408) {
        int i = (bid - 360) * 256 + t;        // < 12288 = 64*192
        if (i < OUT_ * DDIM_) {
            float v = ow[i];
            unsigned short hi = f2bf(v);
            wbp[i] = hi;
            wbp[OUT_ * DDIM_ + i] = f2bf(v - bf2f(hi));
        }
    } else if (bid == 408) {
        // zero part1|part2: (INTER_+BC_)*8 float2 = 2752 floats
        for (int i = t; i < (INTER_ + BC_) * 8 * 2; i += 256) pz[i] = 0.f;
    } else {
        // basesM: 2mt * 2ks * 64lane * 8j = 2048 bf16
        for (int i = t; i < 2048; i += 256) {
            int j = i & 7, lane = (i >> 3) & 63, sk = (i >> 9) & 1, mt = i >> 10;
            int q = lane >> 4, n15 = lane & 15;
            int tp2 = mt * 16 + n15;
            int ky = sk * 4 + q, kx = j;
            unsigned short v = 0;
            if (tp2 < TB_ && ky < 7 && kx < 7)
                v = f2bf(bases[tp2 * K2_ + ky * 7 + kx]);
            basesM[i] = v;
        }
    }
}

// ---------------------------------------------------------------------------
// k_front: horizontal fusion of (pconv-MFMA | conv1-direct), 1:1 interleave.
// pconv as MFMA GEMM: P[tp2][px] = sum_k bases[tp2][k] * patch[k][px],
// k' = ky*8+kx. B-col n15 -> pixels {2n15, 2n15+1, 2n15+32, 2n15+33}: the
// aligned u32 window d[0..4] (elements 2n15..2n15+9, 4B-aligned) yields f0
// directly and f1 by 16-bit funnel shift (v_alignbit). Adjacent pixel pairs
// give 8B-coalesced dwordx2 P2 stores.
__global__ __launch_bounds__(256) void k_front(const float* __restrict__ x,
                                               const unsigned short* __restrict__ basesM,
                                               const unsigned short* __restrict__ wb1,
                                               const float* __restrict__ b1,
                                               unsigned int* __restrict__ P2,
                                               float* __restrict__ y1,
                                               float2* __restrict__ part1) {
    __shared__ __align__(16) char smem[16896];
    int bid = blockIdx.x, t = threadIdx.x;
    int g = bid >> 1, fr = bid & 1;      // 1:1 interleave

    if (fr == 0) {
        // ---- pconv family (MFMA): pid -> (n, c, rg) ----
        unsigned short* xt = (unsigned short*)smem;   // [23][72] bf16, col shift 3
        int rg = g & 3;
        int c  = (g >> 2) & 31;
        int n  = g >> 7;
        int h0 = rg << 4;
        int lane = t & 63, wv = t >> 6;
        int q = lane >> 4, n15 = lane & 15;

        const float* xc = x + (((size_t)n * C_ + c) << 12);
        for (int i = t; i < 23 * 72; i += 256) {
            int r = i / 72, cl = i % 72;
            int gr = h0 - 3 + r, gc = cl - 3;
            float v = 0.f;
            if (r < 22 && gr >= 0 && gr < H_ && gc >= 0 && gc < W_)
                v = xc[(gr << 6) + gc];
            xt[i] = f2bf(v);
        }
        __syncthreads();

        short8 afr[2][2];
        #pragma unroll
        for (int mt = 0; mt < 2; mt++)
            #pragma unroll
            for (int sk = 0; sk < 2; sk++)
                afr[mt][sk] = *(const short8*)(basesM + ((mt * 2 + sk) * 64 + lane) * 8);

        #pragma unroll 1
        for (int rr = 0; rr < 4; rr++) {
            int hrow = wv * 4 + rr;          // 0..15
            int h = h0 + hrow;
            f32x4 acc[4][2];                 // [cc: px 2n15,2n15+1,2n15+32,2n15+33][mt]
            #pragma unroll
            for (int cc = 0; cc < 4; cc++) {
                acc[cc][0] = (f32x4){0.f, 0.f, 0.f, 0.f};
                acc[cc][1] = (f32x4){0.f, 0.f, 0.f, 0.f};
            }
            #pragma unroll
            for (int sk = 0; sk < 2; sk++) {
                // aligned u32 window: elements 2n15.. (u32 index row*36+n15)
                const unsigned int* rp32 = (const unsigned int*)xt +
                                           (hrow + sk * 4 + q) * 36 + n15;
                unsigned int d0 = rp32[0], d1 = rp32[1], d2 = rp32[2],
                             d3 = rp32[3], d4 = rp32[4];
                unsigned int e0 = rp32[16], e1 = rp32[17], e2 = rp32[18],
                             e3 = rp32[19], e4 = rp32[20];
                union { unsigned int u[4]; short8 s; } f0, f1, f2v, f3v;
                f0.u[0] = d0; f0.u[1] = d1; f0.u[2] = d2; f0.u[3] = d3;
                f1.u[0] = (d0 >> 16) | (d1 << 16);
                f1.u[1] = (d1 >> 16) | (d2 << 16);
                f1.u[2] = (d2 >> 16) | (d3 << 16);
                f1.u[3] = (d3 >> 16) | (d4 << 16);
                f2v.u[0] = e0; f2v.u[1] = e1; f2v.u[2] = e2; f2v.u[3] = e3;
                f3v.u[0] = (e0 >> 16) | (e1 << 16);
                f3v.u[1] = (e1 >> 16) | (e2 << 16);
                f3v.u[2] = (e2 >> 16) | (e3 << 16);
                f3v.u[3] = (e3 >> 16) | (e4 << 16);
                acc[0][0] = __builtin_amdgcn_mfma_f32_16x16x32_bf16(afr[0][sk], f0.s, acc[0][0], 0, 0, 0);
                acc[0][1] = __builtin_amdgcn_mfma_f32_16x16x32_bf16(afr[1][sk], f0.s, acc[0][1], 0, 0, 0);
                acc[1][0] = __builtin_amdgcn_mfma_f32_16x16x32_bf16(afr[0][sk], f1.s, acc[1][0], 0, 0, 0);
                acc[1][1] = __builtin_amdgcn_mfma_f32_16x16x32_bf16(afr[1][sk], f1.s, acc[1][1], 0, 0, 0);
                acc[2][0] = __builtin_amdgcn_mfma_f32_16x16x32_bf16(afr[0][sk], f2v.s, acc[2][0], 0, 0, 0);
                acc[2][1] = __builtin_amdgcn_mfma_f32_16x16x32_bf16(afr[1][sk], f2v.s, acc[2][1], 0, 0, 0);
                acc[3][0] = __builtin_amdgcn_mfma_f32_16x16x32_bf16(afr[0][sk], f3v.s, acc[3][0], 0, 0, 0);
                acc[3][1] = __builtin_amdgcn_mfma_f32_16x16x32_bf16(afr[1][sk], f3v.s, acc[3][1], 0, 0, 0);
            }
            // stores: D row m=q*4+reg -> tp2; pairs (reg0,reg1)->tp=2q,
            // (reg2,reg3)->tp=2q+1; mt=1 q==0 -> tp=8. Adjacent px pair ->
            // one 8B store at col 2n15 (+32 for pp=1).
            size_t pb = ((size_t)n * P2CH_) << 12;
            #pragma unroll
            for (int pp = 0; pp < 2; pp++) {
                int ccb = pp * 2;
                int colb = 2 * n15 + pp * 32;
                unsigned int lo0 = (unsigned int)f2bf(acc[ccb][0][0]) |
                                   ((unsigned int)f2bf(acc[ccb][0][1]) << 16);
                unsigned int hi0 = (unsigned int)f2bf(acc[ccb + 1][0][0]) |
                                   ((unsigned int)f2bf(acc[ccb + 1][0][1]) << 16);
                unsigned int lo1 = (unsigned int)f2bf(acc[ccb][0][2]) |
                                   ((unsigned int)f2bf(acc[ccb][0][3]) << 16);
                unsigned int hi1 = (unsigned int)f2bf(acc[ccb + 1][0][2]) |
                                   ((unsigned int)f2bf(acc[ccb + 1][0][3]) << 16);
                *(unsigned long long*)&P2[pb + (((size_t)(2 * q) * 32 + c) << 12) + (h << 6) + colb] =
                    (unsigned long long)lo0 | ((unsigned long long)hi0 << 32);
                *(unsigned long long*)&P2[pb + (((size_t)(2 * q + 1) * 32 + c) << 12) + (h << 6) + colb] =
                    (unsigned long long)lo1 | ((unsigned long long)hi1 << 32);
                if (q == 0) {
                    unsigned int lo8 = (unsigned int)f2bf(acc[ccb][1][0]) |
                                       ((unsigned int)f2bf(acc[ccb][1][1]) << 16);
                    unsigned int hi8 = (unsigned int)f2bf(acc[ccb + 1][1][0]) |
                                       ((unsigned int)f2bf(acc[ccb + 1][1][1]) << 16);
                    *(unsigned long long*)&P2[pb + (((size_t)8 * 32 + c) << 12) + (h << 6) + colb] =
                        (unsigned long long)lo8 | ((unsigned long long)hi8 << 32);
                }
            }
        }
    } else {
        // ---- conv1 family: COG=32, ROWS=1, weights from global wb1 ----
        // LDS carve: sx1[198][40] bf16 (15840B) | sbp[4][64] f32 (1024B)
        unsigned short* sx1 = (unsigned short*)smem;
        float* sbp = (float*)(sx1 + 198 * 40);   // offset 15840 (16-aligned)

        int cid = g;                   // 0..1023
        int n = cid >> 7;              // 0..7
        int rem = cid & 127;
        int co0 = (rem & 1) << 5;      // 2 co-halves of 32
        int h0 = rem >> 1;             // 64 rows
        int lane = t & 63, wv = t >> 6;
        int q = lane >> 4, n15 = lane & 15;

        // stage x tile: rows h0-1..h0+1, cols 1..64 (x cols 0..63), 32 ch, bf16
        for (int e = t; e < 1536; e += 256) {
            int c = e & 31, rc4 = e >> 5;        // rc4 in 0..47
            int r = rc4 >> 4, cq = rc4 & 15;     // r 0..2, cq 0..15
            int hh = h0 - 1 + r;
            bool rok = (hh >= 0 && hh < H_);
            float4 v = {0.f, 0.f, 0.f, 0.f};
            if (rok) v = *(const float4*)(x + (((size_t)n * C_ + c) << 12) + (hh << 6) + cq * 4);
            unsigned short* d = sx1 + (r * 66 + 1 + cq * 4) * 40 + c;
            d[0]   = f2bf(v.x);
            d[40]  = f2bf(v.y);
            d[80]  = f2bf(v.z);
            d[120] = f2bf(v.w);
        }
        // border zeros: cols 0 and 65, 3 rows x 32 channels
        if (t < 96) {
            int c = t & 31, r = t >> 5;
            sx1[(r * 66 + 0) * 40 + c] = 0;
            sx1[(r * 66 + 65) * 40 + c] = 0;
        }
        __syncthreads();

        f32x4 acc[2];
        acc[0] = (f32x4){0.f, 0.f, 0.f, 0.f};
        acc[1] = (f32x4){0.f, 0.f, 0.f, 0.f};
        #pragma unroll
        for (int s = 0; s < 9; s++) {
            int dy = s / 3, dx = s % 3;
            short8 bfr = *(const short8*)(sx1 + (dy * 66 + wv * 16 + n15 + dx) * 40 + q * 8);
            #pragma unroll
            for (int mt = 0; mt < 2; mt++) {
                short8 afr = *(const short8*)(wb1 + s * 2048 + (co0 + mt * 16 + n15) * 32 + q * 8);
                acc[mt] = __builtin_amdgcn_mfma_f32_16x16x32_bf16(afr, bfr, acc[mt], 0, 0, 0);
            }
        }

        // epilogue: store y1 + BN1 partial stats
        int wcol = wv * 16 + n15;
        float sa[2][4], sa2[2][4];
        #pragma unroll
        for (int mt = 0; mt < 2; mt++)
            #pragma unroll
            for (int reg = 0; reg < 4; reg++) {
                int co = co0 + mt * 16 + q * 4 + reg;
                float v = acc[mt][reg] + b1[co];
                y1[(((size_t)n * INTER_ + co) << 12) + (h0 << 6) + wcol] = v;
                sa[mt][reg] = v; sa2[mt][reg] = v * v;
            }
        #pragma unroll
        for (int mt = 0; mt < 2; mt++)
            #pragma unroll
            for (int reg = 0; reg < 4; reg++) {
                float s = sa[mt][reg], s2 = sa2[mt][reg];
                #pragma unroll
                for (int off = 1; off < 16; off <<= 1) {
                    s += __shfl_xor(s, off);
                    s2 += __shfl_xor(s2, off);
                }
                if (n15 == 0) {
                    int cl = mt * 16 + q * 4 + reg;
                    sbp[wv * 64 + cl * 2] = s;
                    sbp[wv * 64 + cl * 2 + 1] = s2;
                }
            }
        __syncthreads();
        if (t < 32) {
            float s = 0.f, s2 = 0.f;
            #pragma unroll
            for (int w = 0; w < 4; w++) { s += sbp[w * 64 + t * 2]; s2 += sbp[w * 64 + t * 2 + 1]; }
            atomicAdd(&part1[((co0 + t) << 3) + n].x, s);
            atomicAdd(&part1[((co0 + t) << 3) + n].y, s2);
        }
    }
}

// ---------------------------------------------------------------------------
// MFMA conv3x3 (pad=1), stage-once (weights in LDS -- the verified-fastest
// configuration; direct-global weights measured +1.8us in round 16).
// BN partial stats fused into epilogue. (Used only for conv2.)
template<int CIN, int COG, int ROWS, int WPAD, int NCOQ>
__global__ __launch_bounds__(256) void k_conv3(const unsigned short* __restrict__ xb,
                                               const unsigned short* __restrict__ wb,
                                               const float* __restrict__ bias,
                                               float* __restrict__ y,
                                               float2* __restrict__ part,
                                               int COUT_real) {
    constexpr int CPAD = CIN + 8;
    constexpr int NSLC = (ROWS + 2) * 66;
    constexpr int MT = COG / 16;
    constexpr int NTW = ROWS;
    constexpr int KSTEPS = CIN / 32;
    __shared__ unsigned short sx[NSLC * CPAD];
    __shared__ unsigned short sw[9 * COG * CPAD];
    __shared__ float sbp[4][COG * 2];

    int bid = blockIdx.x;
    int coq = bid % NCOQ;
    int rp = (bid / NCOQ) % (H_ / ROWS);
    int n = bid / (NCOQ * (H_ / ROWS));
    int h0 = rp * ROWS;
    int co0 = coq * COG;
    int t = threadIdx.x;
    int lane = t & 63, wv = t >> 6;
    int q = lane >> 4, n15 = lane & 15;

    {
        const unsigned int* xg = (const unsigned int*)xb + (size_t)n * HW_ * (CIN / 2);
        unsigned int* sxd = (unsigned int*)sx;
        constexpr int DW = CIN / 2;
        constexpr int DWPT = DW / 8;
        int part_ = t & 7;
        for (int sl = (t >> 3); sl < NSLC; sl += 32) {
            int r = sl / 66, col = sl % 66;
            int hh = h0 - 1 + r, ww = col - 1;
            unsigned int v[DWPT];
            #pragma unroll
            for (int i = 0; i < DWPT; i++) v[i] = 0;
            if (hh >= 0 && hh < H_ && ww >= 0 && ww < W_) {
                const unsigned int* gp = xg + (size_t)(hh * W_ + ww) * DW + part_ * DWPT;
                #pragma unroll
                for (int i = 0; i < DWPT; i++) v[i] = gp[i];
            }
            unsigned int* d = sxd + sl * (CPAD / 2) + part_ * DWPT;
            #pragma unroll
            for (int i = 0; i < DWPT; i++) d[i] = v[i];
        }
    }
    {
        const unsigned int* wg = (const unsigned int*)wb;
        unsigned int* swd = (unsigned int*)sw;
        constexpr int TOT = 9 * COG * (CIN / 2);
        for (int e = t; e < TOT; e += 256) {
            int s_co = e / (CIN / 2), cw = e % (CIN / 2);
            int s = s_co / COG, co = s_co % COG;
            swd[s_co * (CPAD / 2) + cw] = wg[((size_t)s * WPAD + co0 + co) * (CIN / 2) + cw];
        }
    }
    __syncthreads();

    f32x4 acc[NTW][MT];
    #pragma unroll
    for (int a = 0; a < NTW; a++)
        #pragma unroll
        for (int m = 0; m < MT; m++) acc[a][m] = (f32x4){0.f, 0.f, 0.f, 0.f};

    #pragma unroll
    for (int s = 0; s < 9; s++) {
        int dy = s / 3, dx = s % 3;
        #pragma unroll
        for (int kc = 0; kc < KSTEPS; kc++) {
            int ci0 = kc * 32;
            short8 bfr[NTW];
            #pragma unroll
            for (int ntl = 0; ntl < NTW; ntl++) {
                int nt = wv * NTW + ntl;
                int r_out = nt >> 2, col0 = (nt & 3) * 16;
                bfr[ntl] = *(const short8*)(sx + ((r_out + dy) * 66 + col0 + n15 + dx) * CPAD + ci0 + q * 8);
            }
            #pragma unroll
            for (int mt = 0; mt < MT; mt++) {
                short8 afr = *(const short8*)(sw + ((s * COG) + mt * 16 + n15) * CPAD + ci0 + q * 8);
                #pragma unroll
                for (int ntl = 0; ntl < NTW; ntl++)
                    acc[ntl][mt] = __builtin_amdgcn_mfma_f32_16x16x32_bf16(afr, bfr[ntl], acc[ntl][mt], 0, 0, 0);
            }
        }
    }

    float sacc[MT][4], sacc2[MT][4];
    #pragma unroll
    for (int mt = 0; mt < MT; mt++)
        #pragma unroll
        for (int reg = 0; reg < 4; reg++) { sacc[mt][reg] = 0.f; sacc2[mt][reg] = 0.f; }

    #pragma unroll
    for (int ntl = 0; ntl < NTW; ntl++) {
        int nt = wv * NTW + ntl;
        int h = h0 + (nt >> 2), wcol = (nt & 3) * 16 + n15;
        #pragma unroll
        for (int mt = 0; mt < MT; mt++) {
            #pragma unroll
            for (int reg = 0; reg < 4; reg++) {
                int co = co0 + mt * 16 + q * 4 + reg;
                if (co < COUT_real) {
                    float v = acc[ntl][mt][reg] + bias[co];
                    y[(((size_t)n * COUT_real + co) << 12) + h * W_ + wcol] = v;
                    sacc[mt][reg] += v;
                    sacc2[mt][reg] += v * v;
                }
            }
        }
    }

    #pragma unroll
    for (int mt = 0; mt < MT; mt++)
        #pragma unroll
        for (int reg = 0; reg < 4; reg++) {
            float s = sacc[mt][reg], s2 = sacc2[mt][reg];
            #pragma unroll
            for (int off = 1; off < 16; off <<= 1) {
                s += __shfl_xor(s, off);
                s2 += __shfl_xor(s2, off);
            }
            if (n15 == 0) {
                int cl = mt * 16 + q * 4 + reg;
                sbp[wv][cl * 2] = s;
                sbp[wv][cl * 2 + 1] = s2;
            }
        }
    __syncthreads();
    if (t < COG) {
        float s = 0.f, s2 = 0.f;
        #pragma unroll
        for (int w2 = 0; w2 < 4; w2++) { s += sbp[w2][t * 2]; s2 += sbp[w2][t * 2 + 1]; }
        int co = co0 + t;
        if (co < COUT_real) {
            atomicAdd(&part[(co << 3) + n].x, s);
            atomicAdd(&part[(co << 3) + n].y, s2);
        }
    }
}

// ---------------------------------------------------------------------------
// y1 NCHW f32 -> tanh(bn) -> y1b NHWC bf16
__global__ __launch_bounds__(256) void k_bntr(const float* __restrict__ y1,
                                              const float2* __restrict__ part,
                                              const float* __restrict__ g,
                                              const float* __restrict__ bb,
                                              unsigned short* __restrict__ y1b) {
    __shared__ unsigned short sT[64 * 68];
    __shared__ float scs[INTER_], shs[INTER_];
    int bid = blockIdx.x, t = threadIdx.x;
    int n = bid >> 6, hw0 = (bid << 6) & 4095;
    if (t < INTER_) {
        float s = 0.f, s2 = 0.f;
        #pragma unroll
        for (int j = 0; j < 8; j++) { float2 p = part[t * 8 + j]; s += p.x; s2 += p.y; }
        float mu = s / (float)NHW_, var = s2 / (float)NHW_ - mu * mu;
        float sc = g[t] * rsqrtf(var + 1e-5f);
        scs[t] = sc; shs[t] = bb[t] - mu * sc;
    }
    __syncthreads();
    for (int i = t; i < 4096; i += 256) {
        int c = i >> 6, px = i & 63;
        float v = y1[(((size_t)n * INTER_ + c) << 12) + hw0 + px];
        sT[px * 68 + c] = f2bf(tanhf(v * scs[c] + shs[c]));
    }
    __syncthreads();
    unsigned int* yd = (unsigned int*)y1b;
    for (int i = t; i < 2048; i += 256) {
        int px = i >> 5, cw = i & 31;
        unsigned int lo = sT[px * 68 + cw * 2], hi = sT[px * 68 + cw * 2 + 1];
        yd[(((size_t)n << 12) + hw0 + px) * 32 + cw] = lo | (hi << 16);
    }
}

// ---------------------------------------------------------------------------
// Fused tail: hoisted P2 loads, packed-fp32 phase 2, split-bf16 MFMA proj.
#define YPAD_ 97
__global__ __launch_bounds__(256) void k_ytail(const float* __restrict__ y2,
                                               const float2* __restrict__ part,
                                               const float* __restrict__ g,
                                               const float* __restrict__ bb,
                                               const unsigned int* __restrict__ P2,
                                               const unsigned short* __restrict__ wbp,
                                               const float* __restrict__ out_b,
                                               float* __restrict__ out) {
    __shared__ float scs[BC_], shs[BC_];
    __shared__ float cfs[BC_][32];
    __shared__ unsigned int sYh[32 * YPAD_];
    __shared__ unsigned int sYl[32 * YPAD_];

    int bid = blockIdx.x;
    int n = bid >> 7, px0 = (bid & 127) << 5;
    int t = threadIdx.x;

    int px = t & 31, cg = t >> 5;
    unsigned int u[4][9];
    {
        const unsigned int* Pb = P2 + (((size_t)n * P2CH_) << 12) + px0 + px;
        #pragma unroll
        for (int cc = 0; cc < 4; cc++) {
            int c = cg * 4 + cc;
            #pragma unroll
            for (int tp = 0; tp < 9; tp++)
                u[cc][tp] = Pb[(size_t)(tp * 32 + c) << 12];
        }
    }

    if (t < BC_) {
        float s = 0.f, s2 = 0.f;
        #pragma unroll
        for (int j = 0; j < 8; j++) { float2 p = part[t * 8 + j]; s += p.x; s2 += p.y; }
        float mu = s / (float)NHW_, var = s2 / (float)NHW_ - mu * mu;
        float sc = g[t] * rsqrtf(var + 1e-5f);
        scs[t] = sc; shs[t] = bb[t] - mu * sc;
    }
    __syncthreads();

    for (int i = t; i < BC_ * 32; i += 256) {
        int ch = i >> 5, pxx = i & 31;
        float v = y2[(((size_t)n * BC_ + ch) << 12) + px0 + pxx];
        cfs[ch][pxx] = tanhf(v * scs[ch] + shs[ch]);
    }
    __syncthreads();

    {
        f32x2 pv2[2][TB_];
        #pragma unroll
        for (int j = 0; j < 2; j++)
            #pragma unroll
            for (int tp = 0; tp < 9; tp++) {
                pv2[j][2 * tp].x     = __uint_as_float(u[2 * j][tp] << 16);
                pv2[j][2 * tp].y     = __uint_as_float(u[2 * j + 1][tp] << 16);
                pv2[j][2 * tp + 1].x = __uint_as_float(u[2 * j][tp] & 0xffff0000u);
                pv2[j][2 * tp + 1].y = __uint_as_float(u[2 * j + 1][tp] & 0xffff0000u);
            }
        f32x2 ym2[2][NB_];
        #pragma unroll
        for (int j = 0; j < 2; j++)
            #pragma unroll
            for (int m = 0; m < NB_; m++) ym2[j][m] = (f32x2){0.f, 0.f};
        #pragma unroll
        for (int m = 0; m < NB_; m++)
            #pragma unroll
            for (int tt = 0; tt < TB_; tt++) {
                float cfv = cfs[m * TB_ + tt][px];
                f32x2 c2 = (f32x2){cfv, cfv};
                ym2[0][m] += c2 * pv2[0][tt];
                ym2[1][m] += c2 * pv2[1][tt];
            }
        #pragma unroll
        for (int j = 0; j < 2; j++) {
            #pragma unroll
            for (int half = 0; half < 2; half++) {
                int c = cg * 4 + 2 * j + half;
                #pragma unroll
                for (int jj = 0; jj < 3; jj++) {
                    float y0 = half ? ym2[j][2 * jj].y     : ym2[j][2 * jj].x;
                    float y1v = half ? ym2[j][2 * jj + 1].y : ym2[j][2 * jj + 1].x;
                    unsigned short h0 = f2bf(y0);
                    unsigned short h1 = f2bf(y1v);
                    unsigned short l0 = f2bf(y0 - bf2f(h0));
                    unsigned short l1 = f2bf(y1v - bf2f(h1));
                    sYh[px * YPAD_ + c * 3 + jj] = (unsigned int)h0 | ((unsigned int)h1 << 16);
                    sYl[px * YPAD_ + c * 3 + jj] = (unsigned int)l0 | ((unsigned int)l1 << 16);
                }
            }
        }
    }
    __syncthreads();

    int lane = t & 63, wv = t >> 6;
    int q = lane >> 4, n15 = lane & 15;
    f32x4 acc[2];
    acc[0] = (f32x4){0.f, 0.f, 0.f, 0.f};
    acc[1] = (f32x4){0.f, 0.f, 0.f, 0.f};
    #pragma unroll
    for (int ks = 0; ks < 6; ks++) {
        short8 ah = *(const short8*)(wbp + (wv * 16 + n15) * DDIM_ + ks * 32 + q * 8);
        short8 al = *(const short8*)(wbp + OUT_ * DDIM_ + (wv * 16 + n15) * DDIM_ + ks * 32 + q * 8);
        #pragma unroll
        for (int nt = 0; nt < 2; nt++) {
            short8 bh = frag4(sYh + (nt * 16 + n15) * YPAD_ + ks * 16 + q * 4);
            short8 bl = frag4(sYl + (nt * 16 + n15) * YPAD_ + ks * 16 + q * 4);
            acc[nt] = __builtin_amdgcn_mfma_f32_16x16x32_bf16(ah, bh, acc[nt], 0, 0, 0);
            acc[nt] = __builtin_amdgcn_mfma_f32_16x16x32_bf16(ah, bl, acc[nt], 0, 0, 0);
            acc[nt] = __builtin_amdgcn_mfma_f32_16x16x32_bf16(al, bh, acc[nt], 0, 0, 0);
        }
    }
    #pragma unroll
    for (int nt = 0; nt < 2; nt++)
        #pragma unroll
        for (int reg = 0; reg < 4; reg++) {
            int o = wv * 16 + q * 4 + reg;
            out[(((size_t)n * OUT_ + o) << 12) + px0 + nt * 16 + n15] = acc[nt][reg] + out_b[o];
        }
}

extern "C" void kernel_launch(void* const* d_in, const int* in_sizes, int n_in,
                              void* d_out, int out_size, void* d_ws, size_t ws_size,
                              hipStream_t stream) {
    const float* x       = (const float*)d_in[0];
    const float* conv1_w = (const float*)d_in[1];
    const float* conv1_b = (const float*)d_in[2];
    const float* bn1_g   = (const float*)d_in[3];
    const float* bn1_b   = (const float*)d_in[4];
    const float* conv2_w = (const float*)d_in[5];
    const float* conv2_b = (const float*)d_in[6];
    const float* bn2_g   = (const float*)d_in[7];
    const float* bn2_b   = (const float*)d_in[8];
    const float* bases   = (const float*)d_in[9];
    const float* out_w   = (const float*)d_in[10];
    const float* out_b   = (const float*)d_in[11];
    float* out = (float*)d_out;

    float* y1  = (float*)d_ws;                       // 2,097,152 f32
    float* y2  = y1 + (size_t)N_ * INTER_ * HW_;     // 3,538,944 f32
    unsigned int* P2 = (unsigned int*)(y2 + (size_t)N_ * BC_ * HW_); // 9,437,184 dw
    unsigned short* xb  = (unsigned short*)(P2 + (size_t)N_ * P2CH_ * HW_); // (unused, layout kept)
    unsigned short* y1b = xb + (size_t)NHW_ * C_;    // 2,097,152
    unsigned short* wb1 = y1b + (size_t)NHW_ * INTER_; // 18,432
    unsigned short* wb2 = wb1 + 9 * 64 * 32;         // 73,728
    unsigned short* wbp = wb2 + 9 * 128 * 64;        // 24,576 (hi + lo)
    float2* part1 = (float2*)(wbp + 2 * OUT_ * DDIM_); // 64*8
    float2* part2 = part1 + INTER_ * 8;              // 108*8
    unsigned short* basesM = (unsigned short*)(part2 + BC_ * 8); // 2048 bf16

    k_prep<<<410, 256, 0, stream>>>(conv1_w, conv2_w, out_w, bases,
                                    wb1, wb2, wbp, basesM, (float*)part1);

    k_front<<<2048, 256, 0, stream>>>(x, basesM, wb1, conv1_b, P2, y1, part1);

    k_bntr<<<512, 256, 0, stream>>>(y1, part1, bn1_g, bn1_b, y1b);

    k_conv3<INTER_, 16, 2, 128, 7><<<N_ * 32 * 7, 256, 0, stream>>>(
        y1b, wb2, conv2_b, y2, part2, BC_);

    k_ytail<<<1024, 256, 0, stream>>>(y2, (const float2*)part2, bn2_g, bn2_b,
                                      P2, wbp, out_b, out);
}